// Round 8
// baseline (83.685 us; speedup 1.0000x reference)
//
#include <hip/hip_runtime.h>
#include <hip/hip_bf16.h>

#define BDIM 256
#define NDIM 512
#define CDIM 1000
#define RDIM 64
#define BK 64
#define NT (NDIM / BK)   // 8 K-tiles

typedef __attribute__((ext_vector_type(4))) float f32x4;
typedef __attribute__((ext_vector_type(8))) short bf16x8;

__device__ __forceinline__ uint32_t pk2(float lo, float hi) {
    unsigned short l = __builtin_bit_cast(unsigned short, __float2bfloat16(lo));
    unsigned short h = __builtin_bit_cast(unsigned short, __float2bfloat16(hi));
    return ((uint32_t)h << 16) | (uint32_t)l;
}

__device__ __forceinline__ void gload16(const void* g, void* l) {
    __builtin_amdgcn_global_load_lds(
        (const __attribute__((address_space(1))) void*)g,
        (__attribute__((address_space(3))) void*)l, 16, 0, 0);
}

// ---------------------------------------------------------------------------
// Pre-pass (proven r2/r3/r7): x fp32 [256][512] -> bf16 swizzled BK=64 tile
// images in d_ws. Tile t: byte P = row*128 + sIn, sIn = uIn ^ ((row&7)<<4).
// ---------------------------------------------------------------------------
__global__ __launch_bounds__(256)
void Mahalanobis_xconv_kernel(const float* __restrict__ x, uint4* __restrict__ xws)
{
    const int tid = blockIdx.x * 256 + threadIdx.x;   // 0..16383
    const int t   = tid >> 11;                        // tile 0..7
    const int rem = tid & 2047;
    const int row = rem >> 3;                         // 0..255
    const int sIn = (rem & 7) << 4;                   // swizzled inner byte
    const int uIn = sIn ^ ((row & 7) << 4);           // unswizzled inner byte
    const int col0 = t * BK + (uIn >> 1);
    const float4* src = reinterpret_cast<const float4*>(x + (size_t)row * NDIM + col0);
    const float4 a = src[0], b = src[1];
    uint4 pk = {pk2(a.x, a.y), pk2(a.z, a.w), pk2(b.x, b.y), pk2(b.z, b.w)};
    xws[tid] = pk;
}

// ---------------------------------------------------------------------------
// Main kernel: 2 classes/block (grid 500) -> total load traffic 262 MB.
// r7 loop skeleton: ONE __syncthreads per iter; x via gload_lds (wave-private
// slices, wave-local lgkmcnt fence); W(t+1) q-mapped coalesced reg loads
// issued at top of iter, converted to bf16 swizzled LDS write-late (after
// MFMA) with fused fp32 Sb partials. No manual vmcnt anywhere.
// ---------------------------------------------------------------------------
__global__ __launch_bounds__(256, 2)
void Mahalanobis_72834055405642_kernel(const char* __restrict__ xws,
                                       const float* __restrict__ w,
                                       const float* __restrict__ bias,
                                       float* __restrict__ out)
{
    __shared__ alignas(16) char  lds_x[BDIM * BK * 2];      // 32 KB, wave-sliced
    __shared__ alignas(16) char  lds_w[2][128 * BK * 2];    // 2 x 16 KB bf16
    __shared__ alignas(16) float bias_lds[2 * NDIM];        // 4 KB (2 classes)
    __shared__ float sb_lds[128];                           // 512 B

    const int tid  = threadIdx.x;
    const int lane = tid & 63;
    const int wv   = tid >> 6;
    const int l15  = lane & 15;
    const int lhi  = lane >> 4;
    const int c0   = blockIdx.x * 2;

    // W staging map: thread covers tile rows r0+16i (i=0..7), col-quarter q
    const int r0 = tid >> 4;        // 0..15
    const int q  = tid & 15;        // 0..15
    const float* wst = w + (size_t)c0 * (RDIM * NDIM) + (size_t)r0 * NDIM + q * 4;

    const int swr = (l15 & 7) << 4;

    f32x4 acc[4][8];
    #pragma unroll
    for (int m = 0; m < 4; ++m)
        #pragma unroll
        for (int n = 0; n < 8; ++n)
            acc[m][n] = (f32x4){0.f, 0.f, 0.f, 0.f};

    float sbq[8] = {0.f, 0.f, 0.f, 0.f, 0.f, 0.f, 0.f, 0.f};

    // coalesced W tile load: instr i = 4 contiguous 256B segments per wave
    auto loadW = [&](int t, f32x4* wr) {
        #pragma unroll
        for (int i = 0; i < 8; ++i)
            wr[i] = *reinterpret_cast<const f32x4*>(wst + t * BK + (size_t)i * 16 * NDIM);
    };
    // write-late: fp32 regs -> bf16 swizzled LDS + fused Sb partials
    auto convW = [&](int t, const f32x4* wr, char* dst) {
        #pragma unroll
        for (int i = 0; i < 8; ++i) {
            const int row = r0 + 16 * i;          // 0..127 (class-major)
            const int cl  = row >> 6;
            const f32x4 bv = *reinterpret_cast<const f32x4*>(
                bias_lds + cl * NDIM + t * BK + q * 4);
            sbq[i] += wr[i][0]*bv[0] + wr[i][1]*bv[1] + wr[i][2]*bv[2] + wr[i][3]*bv[3];
            uint2 pk = {pk2(wr[i][0], wr[i][1]), pk2(wr[i][2], wr[i][3])};
            *reinterpret_cast<uint2*>(dst + row * 128 + ((q * 8) ^ ((row & 7) << 4))) = pk;
        }
    };
    auto issueX = [&](int t) {
        #pragma unroll
        for (int qq = 0; qq < 8; ++qq)
            gload16(xws + (size_t)t * 32768 + wv * 8192 + qq * 1024 + (size_t)lane * 16,
                    lds_x + wv * 8192 + qq * 1024);
    };

    // ================= prologue =================
    {   // bias: 2 classes, 1024 floats, 16B/thread
        const f32x4 bv = *reinterpret_cast<const f32x4*>(bias + (size_t)c0 * NDIM + tid * 4);
        *reinterpret_cast<f32x4*>(bias_lds + tid * 4) = bv;
    }
    issueX(0);
    {
        f32x4 wr0[8];
        loadW(0, wr0);
        __syncthreads();          // x(0) + wr0 + bias all complete/visible
        convW(0, wr0, lds_w[0]);
        __syncthreads();          // lds_w[0] writes visible
    }

    // ================= main loop =================
    #pragma unroll
    for (int t = 0; t < NT; ++t) {
        char* wcur = lds_w[t & 1];
        char* wnxt = lds_w[(t & 1) ^ 1];

        // issue W(t+1) early — rides over af-reads + MFMA, consumed write-late
        f32x4 wr[8];
        if (t < NT - 1) loadW(t + 1, wr);

        // A-frags (x slice is wave-private), both k-steps
        bf16x8 af[4][2];
        #pragma unroll
        for (int m = 0; m < 4; ++m) {
            const int row = wv * 64 + m * 16 + l15;
            #pragma unroll
            for (int ks = 0; ks < 2; ++ks)
                af[m][ks] = *reinterpret_cast<const bf16x8*>(
                    lds_x + row * 128 + ((ks * 64 + lhi * 16) ^ swr));
        }

        // wave-local fence: af reads drained -> safe to overwrite own x slice
        if (t < NT - 1) {
            asm volatile("s_waitcnt lgkmcnt(0)" ::: "memory");
            __builtin_amdgcn_sched_barrier(0);
            issueX(t + 1);
        }

        // MFMA phase: B-frags JIT from current bf16 W tile
        #pragma unroll
        for (int ks = 0; ks < 2; ++ks) {
            bf16x8 bfr[8];
            #pragma unroll
            for (int n = 0; n < 8; ++n) {
                const int row = n * 16 + l15;
                bfr[n] = *reinterpret_cast<const bf16x8*>(
                    wcur + row * 128 + ((ks * 64 + lhi * 16) ^ swr));
            }
            #pragma unroll
            for (int m = 0; m < 4; ++m)
                #pragma unroll
                for (int n = 0; n < 8; ++n)
                    acc[m][n] = __builtin_amdgcn_mfma_f32_16x16x32_bf16(
                        af[m][ks], bfr[n], acc[m][n], 0, 0, 0);
        }

        // write-late convert (compiler inserts counted vmcnt for wr)
        if (t < NT - 1) convW(t + 1, wr, wnxt);

        __syncthreads();   // drains x(t+1) gloads + W ds_writes; orders reuse
    }

    // ---- Sb: butterfly over the 16 q-lanes, publish rows r0+16i
    #pragma unroll
    for (int i = 0; i < 8; ++i) {
        sbq[i] += __shfl_xor(sbq[i], 1);
        sbq[i] += __shfl_xor(sbq[i], 2);
        sbq[i] += __shfl_xor(sbq[i], 4);
        sbq[i] += __shfl_xor(sbq[i], 8);
    }
    if (q == 0) {
        #pragma unroll
        for (int i = 0; i < 8; ++i)
            sb_lds[r0 + 16 * i] = sbq[i];
    }
    __syncthreads();

    float sb[8];
    #pragma unroll
    for (int n = 0; n < 8; ++n) sb[n] = sb_lds[n * 16 + l15];

    // ---- epilogue (r1-proven): out[b, c0 + {0,1}] = sum_r (S - Sb)^2
    #pragma unroll
    for (int m = 0; m < 4; ++m) {
        #pragma unroll
        for (int rg = 0; rg < 4; ++rg) {
            float p0 = 0.f, p1 = 0.f;
            #pragma unroll
            for (int n = 0; n < 4; ++n) {
                const float d0 = acc[m][n][rg]     - sb[n];
                const float d1 = acc[m][n + 4][rg] - sb[n + 4];
                p0 += d0 * d0;
                p1 += d1 * d1;
            }
            #pragma unroll
            for (int s = 1; s < 16; s <<= 1) {
                p0 += __shfl_xor(p0, s);
                p1 += __shfl_xor(p1, s);
            }
            if (l15 == 0) {
                const int b = wv * 64 + m * 16 + lhi * 4 + rg;
                float2 o2 = {p0, p1};
                *reinterpret_cast<float2*>(out + (size_t)b * CDIM + c0) = o2;
            }
        }
    }
}

// ---------------------------------------------------------------------------
// Fallback (round-3 proven kernel) for ws_size < 256 KB
// ---------------------------------------------------------------------------
__global__ __launch_bounds__(256, 4)
void Mahalanobis_fallback_kernel(const float* __restrict__ x,
                                 const float* __restrict__ w,
                                 const float* __restrict__ bias,
                                 float* __restrict__ out)
{
    __shared__ alignas(16) char lds_x[BDIM * BK * 2];
    __shared__ alignas(16) char lds_w[RDIM * BK * 2];
    __shared__ float sb_lds[RDIM];

    const int tid  = threadIdx.x;
    const int lane = tid & 63;
    const int wv   = tid >> 6;
    const int l15  = lane & 15;
    const int lhi  = lane >> 4;
    const int c0   = blockIdx.x;

    const int jrow = tid >> 2;
    const int jq   = tid & 3;
    const float* wbase = w + (size_t)c0 * (RDIM * NDIM) + (size_t)jrow * NDIM + jq * 16;
    const float* bbase = bias + (size_t)c0 * NDIM + jq * 16;

    f32x4 acc[4][4];
    #pragma unroll
    for (int m = 0; m < 4; ++m)
        #pragma unroll
        for (int n = 0; n < 4; ++n)
            acc[m][n] = (f32x4){0.f, 0.f, 0.f, 0.f};

    float sbp = 0.f;
    const int swr = (l15 & 7) << 4;
    const int sww = (jrow & 7) << 4;
    const int xrow = tid >> 2;
    const int xq   = tid & 3;

    for (int t = 0; t < NT; ++t) {
        const float4* wsrc = reinterpret_cast<const float4*>(wbase + t * BK);
        const float4* bsrc = reinterpret_cast<const float4*>(bbase + t * BK);
        float4 w0 = wsrc[0], w1 = wsrc[1], w2 = wsrc[2], w3 = wsrc[3];
        float4 b0 = bsrc[0], b1 = bsrc[1], b2 = bsrc[2], b3 = bsrc[3];

        #pragma unroll
        for (int p = 0; p < 4; ++p) {
            const int r = p * 64 + xrow;
            const float4* s = reinterpret_cast<const float4*>(
                x + (size_t)r * NDIM + t * BK + xq * 16);
            float4 va = s[0], vb = s[1], vc = s[2], vd = s[3];
            uint4 pa = {pk2(va.x, va.y), pk2(va.z, va.w), pk2(vb.x, vb.y), pk2(vb.z, vb.w)};
            uint4 pb = {pk2(vc.x, vc.y), pk2(vc.z, vc.w), pk2(vd.x, vd.y), pk2(vd.z, vd.w)};
            const int sw = (r & 7) << 4;
            char* rowp = lds_x + r * 128;
            *reinterpret_cast<uint4*>(rowp + ((xq * 32) ^ sw))      = pa;
            *reinterpret_cast<uint4*>(rowp + ((xq * 32 + 16) ^ sw)) = pb;
        }

        sbp += w0.x*b0.x + w0.y*b0.y + w0.z*b0.z + w0.w*b0.w
             + w1.x*b1.x + w1.y*b1.y + w1.z*b1.z + w1.w*b1.w
             + w2.x*b2.x + w2.y*b2.y + w2.z*b2.z + w2.w*b2.w
             + w3.x*b3.x + w3.y*b3.y + w3.z*b3.z + w3.w*b3.w;
        {
            char* rowp = lds_w + jrow * 128;
            uint4 pa = {pk2(w0.x, w0.y), pk2(w0.z, w0.w), pk2(w1.x, w1.y), pk2(w1.z, w1.w)};
            uint4 pb = {pk2(w2.x, w2.y), pk2(w2.z, w2.w), pk2(w3.x, w3.y), pk2(w3.z, w3.w)};
            *reinterpret_cast<uint4*>(rowp + ((jq * 32) ^ sww))      = pa;
            *reinterpret_cast<uint4*>(rowp + ((jq * 32 + 16) ^ sww)) = pb;
        }

        __syncthreads();

        #pragma unroll
        for (int ks = 0; ks < 2; ++ks) {
            bf16x8 af[4];
            bf16x8 bfr[4];
            #pragma unroll
            for (int m = 0; m < 4; ++m) {
                const int row = wv * 64 + m * 16 + l15;
                af[m] = *reinterpret_cast<const bf16x8*>(
                    lds_x + row * 128 + ((ks * 64 + lhi * 16) ^ swr));
            }
            #pragma unroll
            for (int n = 0; n < 4; ++n) {
                const int row = n * 16 + l15;
                bfr[n] = *reinterpret_cast<const bf16x8*>(
                    lds_w + row * 128 + ((ks * 64 + lhi * 16) ^ swr));
            }
            #pragma unroll
            for (int m = 0; m < 4; ++m)
                #pragma unroll
                for (int n = 0; n < 4; ++n)
                    acc[m][n] = __builtin_amdgcn_mfma_f32_16x16x32_bf16(
                        af[m], bfr[n], acc[m][n], 0, 0, 0);
        }

        __syncthreads();
    }

    sbp += __shfl_xor(sbp, 1);
    sbp += __shfl_xor(sbp, 2);
    if (jq == 0) sb_lds[jrow] = sbp;
    __syncthreads();

    float sb[4];
    #pragma unroll
    for (int n = 0; n < 4; ++n) sb[n] = sb_lds[n * 16 + l15];

    #pragma unroll
    for (int m = 0; m < 4; ++m) {
        #pragma unroll
        for (int rg = 0; rg < 4; ++rg) {
            float p = 0.f;
            #pragma unroll
            for (int n = 0; n < 4; ++n) {
                const float d = acc[m][n][rg] - sb[n];
                p += d * d;
            }
            #pragma unroll
            for (int s = 1; s < 16; s <<= 1)
                p += __shfl_xor(p, s);
            if (l15 == 0) {
                const int b = wv * 64 + m * 16 + lhi * 4 + rg;
                out[(size_t)b * CDIM + c0] = p;
            }
        }
    }
}

extern "C" void kernel_launch(void* const* d_in, const int* in_sizes, int n_in,
                              void* d_out, int out_size, void* d_ws, size_t ws_size,
                              hipStream_t stream) {
    const float* x    = (const float*)d_in[0];
    const float* w    = (const float*)d_in[1];
    const float* bias = (const float*)d_in[2];
    float* out = (float*)d_out;

    if (ws_size >= (size_t)(BDIM * NDIM * 2)) {   // 256 KB bf16 x tile images
        hipLaunchKernelGGL(Mahalanobis_xconv_kernel, dim3(64), dim3(256), 0, stream,
                           x, (uint4*)d_ws);
        hipLaunchKernelGGL(Mahalanobis_72834055405642_kernel, dim3(CDIM / 2), dim3(256),
                           0, stream, (const char*)d_ws, w, bias, out);
    } else {
        hipLaunchKernelGGL(Mahalanobis_fallback_kernel, dim3(CDIM), dim3(256),
                           0, stream, x, w, bias, out);
    }
}

// Round 9
// 42.349 us; speedup vs baseline: 1.9761x; 1.9761x over previous
//
#include <hip/hip_runtime.h>
#include <hip/hip_bf16.h>

#define BDIM 256
#define NDIM 512
#define CDIM 1000
#define RDIM 64
#define BK 64
#define NT (NDIM / BK)   // 8 K-tiles

typedef __attribute__((ext_vector_type(4))) float f32x4;
typedef __attribute__((ext_vector_type(8))) short bf16x8;
typedef __attribute__((ext_vector_type(4))) unsigned int u32x4;

__device__ __forceinline__ uint32_t pk2(float lo, float hi) {
    unsigned short l = __builtin_bit_cast(unsigned short, __float2bfloat16(lo));
    unsigned short h = __builtin_bit_cast(unsigned short, __float2bfloat16(hi));
    return ((uint32_t)h << 16) | (uint32_t)l;
}

__device__ __forceinline__ void gload16(const void* g, void* l) {
    __builtin_amdgcn_global_load_lds(
        (const __attribute__((address_space(1))) void*)g,
        (__attribute__((address_space(3))) void*)l, 16, 0, 0);
}

// ---------------------------------------------------------------------------
// Pre-pass (proven r2/r3/r7): x fp32 [256][512] -> bf16 swizzled BK=64 tile
// images in d_ws. Tile t: byte P = row*128 + sIn, sIn = uIn ^ ((row&7)<<4).
// ---------------------------------------------------------------------------
__global__ __launch_bounds__(256)
void Mahalanobis_xconv_kernel(const float* __restrict__ x, uint4* __restrict__ xws)
{
    const int tid = blockIdx.x * 256 + threadIdx.x;   // 0..16383
    const int t   = tid >> 11;                        // tile 0..7
    const int rem = tid & 2047;
    const int row = rem >> 3;                         // 0..255
    const int sIn = (rem & 7) << 4;                   // swizzled inner byte
    const int uIn = sIn ^ ((row & 7) << 4);           // unswizzled inner byte
    const int col0 = t * BK + (uIn >> 1);
    const float4* src = reinterpret_cast<const float4*>(x + (size_t)row * NDIM + col0);
    const float4 a = src[0], b = src[1];
    uint4 pk = {pk2(a.x, a.y), pk2(a.z, a.w), pk2(b.x, b.y), pk2(b.z, b.w)};
    xws[tid] = pk;
}

// ---------------------------------------------------------------------------
// Main kernel: 2 classes/block (grid 500) -> 259 MB total load traffic.
// r1-proven serial 2-barrier skeleton. ALL staging via global_load_lds
// (zero staging VGPRs): x from bf16 swizzled images, W as fp32 with
// pre-swizzled source (inner ^ (row&7)<<5, rule #21 both-sides). B-frags
// JIT-converted fp32->bf16 at read time (r7-proven). Sb fused from the
// fp32 W LDS tile. acc[4][8] in AGPRs; no W tile ever lives in registers.
// ---------------------------------------------------------------------------
__global__ __launch_bounds__(256, 2)
void Mahalanobis_72834055405642_kernel(const char* __restrict__ xws,
                                       const float* __restrict__ w,
                                       const float* __restrict__ bias,
                                       float* __restrict__ out)
{
    __shared__ alignas(16) char  lds_x[BDIM * BK * 2];      // 32 KB bf16, wave-sliced
    __shared__ alignas(16) char  lds_w[128 * BK * 4];       // 32 KB fp32 (128 rows x 256 B)
    __shared__ alignas(16) float bias_lds[2 * NDIM];        // 4 KB
    __shared__ float sb_lds[128];                           // 512 B

    const int tid  = threadIdx.x;
    const int lane = tid & 63;
    const int wv   = tid >> 6;
    const int l15  = lane & 15;
    const int lhi  = lane >> 4;
    const int c0   = blockIdx.x * 2;

    const char* wbytes = reinterpret_cast<const char*>(w) + (size_t)c0 * (RDIM * NDIM * 4);
    const int   winner = (lane & 15) * 16;   // 16B chunk within a 256B W row

    // x staging (r7-proven): wave-uniform LDS base, lane*16 implicit
    auto issueX = [&](int t) {
        #pragma unroll
        for (int q = 0; q < 8; ++q)
            gload16(xws + (size_t)t * 32768 + wv * 8192 + q * 1024 + (size_t)lane * 16,
                    lds_x + wv * 8192 + q * 1024);
    };
    // W staging: 128 class-major tile rows, LDS linear, source pre-swizzled
    auto issueW = [&](int t) {
        #pragma unroll
        for (int q = 0; q < 8; ++q) {
            const int row = wv * 32 + q * 4 + (lane >> 4);            // 0..127
            gload16(wbytes + (size_t)row * 2048 + t * 256 + (winner ^ ((row & 7) << 5)),
                    lds_w + wv * 8192 + q * 1024);
        }
    };

    const int swr   = (l15 & 7) << 4;     // x-image read swizzle (bf16)
    const int jrow2 = tid >> 1;           // Sb: tile row 0..127
    const int jh    = tid & 1;            // Sb: 32-float half
    const int swj   = (jrow2 & 7) << 5;

    f32x4 acc[4][8];
    #pragma unroll
    for (int m = 0; m < 4; ++m)
        #pragma unroll
        for (int n = 0; n < 8; ++n)
            acc[m][n] = (f32x4){0.f, 0.f, 0.f, 0.f};

    float sbp = 0.f;

    // ---- prologue: bias -> LDS (16 B/thread)
    {
        const f32x4 bv = *reinterpret_cast<const f32x4*>(bias + (size_t)c0 * NDIM + tid * 4);
        *reinterpret_cast<f32x4*>(bias_lds + tid * 4) = bv;
    }

    for (int t = 0; t < NT; ++t) {
        issueX(t);
        issueW(t);
        __syncthreads();   // drains gloads (+ bias ds_writes on t=0)

        // A-frags, both k-steps
        bf16x8 af[4][2];
        #pragma unroll
        for (int m = 0; m < 4; ++m) {
            const int row = wv * 64 + m * 16 + l15;
            #pragma unroll
            for (int ks = 0; ks < 2; ++ks)
                af[m][ks] = *reinterpret_cast<const bf16x8*>(
                    lds_x + row * 128 + ((ks * 64 + lhi * 16) ^ swr));
        }

        // Sb partial: this thread covers tile row jrow2, half jh (32 floats)
        {
            const char*  wp = lds_w + jrow2 * 256;
            const float* bl = bias_lds + (jrow2 >> 6) * NDIM + t * BK + jh * 32;
            #pragma unroll
            for (int i = 0; i < 8; ++i) {
                const f32x4 wv4 = *reinterpret_cast<const f32x4*>(
                    wp + ((jh * 128 + i * 16) ^ swj));
                const f32x4 bv4 = *reinterpret_cast<const f32x4*>(bl + i * 4);
                sbp += wv4[0]*bv4[0] + wv4[1]*bv4[1] + wv4[2]*bv4[2] + wv4[3]*bv4[3];
            }
        }

        // MFMA: B-frags JIT from fp32 W tile (transient regs only)
        #pragma unroll
        for (int ks = 0; ks < 2; ++ks) {
            #pragma unroll
            for (int n = 0; n < 8; ++n) {
                const int row = n * 16 + l15;
                const char* pp = lds_w + row * 256 +
                                 ((ks * 128 + lhi * 32) ^ ((row & 7) << 5));
                const f32x4 wlo = *reinterpret_cast<const f32x4*>(pp);
                const f32x4 whi = *reinterpret_cast<const f32x4*>(pp + 16);
                u32x4 pk = {pk2(wlo[0], wlo[1]), pk2(wlo[2], wlo[3]),
                            pk2(whi[0], whi[1]), pk2(whi[2], whi[3])};
                const bf16x8 bw = __builtin_bit_cast(bf16x8, pk);
                #pragma unroll
                for (int m = 0; m < 4; ++m)
                    acc[m][n] = __builtin_amdgcn_mfma_f32_16x16x32_bf16(
                        af[m][ks], bw, acc[m][n], 0, 0, 0);
            }
        }

        __syncthreads();   // all LDS reads done before next-iter overwrite
    }

    // ---- Sb: pair-reduce halves (tid, tid^1), publish row sums
    sbp += __shfl_xor(sbp, 1);
    if (jh == 0) sb_lds[jrow2] = sbp;
    __syncthreads();

    float sb[8];
    #pragma unroll
    for (int n = 0; n < 8; ++n) sb[n] = sb_lds[n * 16 + l15];

    // ---- epilogue (r1-proven): out[b, c0 + {0,1}] = sum_r (S - Sb)^2
    #pragma unroll
    for (int m = 0; m < 4; ++m) {
        #pragma unroll
        for (int rg = 0; rg < 4; ++rg) {
            float p0 = 0.f, p1 = 0.f;
            #pragma unroll
            for (int n = 0; n < 4; ++n) {
                const float d0 = acc[m][n][rg]     - sb[n];
                const float d1 = acc[m][n + 4][rg] - sb[n + 4];
                p0 += d0 * d0;
                p1 += d1 * d1;
            }
            #pragma unroll
            for (int s = 1; s < 16; s <<= 1) {
                p0 += __shfl_xor(p0, s);
                p1 += __shfl_xor(p1, s);
            }
            if (l15 == 0) {
                const int b = wv * 64 + m * 16 + lhi * 4 + rg;
                float2 o2 = {p0, p1};
                *reinterpret_cast<float2*>(out + (size_t)b * CDIM + c0) = o2;
            }
        }
    }
}

// ---------------------------------------------------------------------------
// Fallback (round-3 proven kernel) for ws_size < 256 KB
// ---------------------------------------------------------------------------
__global__ __launch_bounds__(256, 4)
void Mahalanobis_fallback_kernel(const float* __restrict__ x,
                                 const float* __restrict__ w,
                                 const float* __restrict__ bias,
                                 float* __restrict__ out)
{
    __shared__ alignas(16) char lds_x[BDIM * BK * 2];
    __shared__ alignas(16) char lds_w[RDIM * BK * 2];
    __shared__ float sb_lds[RDIM];

    const int tid  = threadIdx.x;
    const int lane = tid & 63;
    const int wv   = tid >> 6;
    const int l15  = lane & 15;
    const int lhi  = lane >> 4;
    const int c0   = blockIdx.x;

    const int jrow = tid >> 2;
    const int jq   = tid & 3;
    const float* wbase = w + (size_t)c0 * (RDIM * NDIM) + (size_t)jrow * NDIM + jq * 16;
    const float* bbase = bias + (size_t)c0 * NDIM + jq * 16;

    f32x4 acc[4][4];
    #pragma unroll
    for (int m = 0; m < 4; ++m)
        #pragma unroll
        for (int n = 0; n < 4; ++n)
            acc[m][n] = (f32x4){0.f, 0.f, 0.f, 0.f};

    float sbp = 0.f;
    const int swr = (l15 & 7) << 4;
    const int sww = (jrow & 7) << 4;
    const int xrow = tid >> 2;
    const int xq   = tid & 3;

    for (int t = 0; t < NT; ++t) {
        const float4* wsrc = reinterpret_cast<const float4*>(wbase + t * BK);
        const float4* bsrc = reinterpret_cast<const float4*>(bbase + t * BK);
        float4 w0 = wsrc[0], w1 = wsrc[1], w2 = wsrc[2], w3 = wsrc[3];
        float4 b0 = bsrc[0], b1 = bsrc[1], b2 = bsrc[2], b3 = bsrc[3];

        #pragma unroll
        for (int p = 0; p < 4; ++p) {
            const int r = p * 64 + xrow;
            const float4* s = reinterpret_cast<const float4*>(
                x + (size_t)r * NDIM + t * BK + xq * 16);
            float4 va = s[0], vb = s[1], vc = s[2], vd = s[3];
            uint4 pa = {pk2(va.x, va.y), pk2(va.z, va.w), pk2(vb.x, vb.y), pk2(vb.z, vb.w)};
            uint4 pb = {pk2(vc.x, vc.y), pk2(vc.z, vc.w), pk2(vd.x, vd.y), pk2(vd.z, vd.w)};
            const int sw = (r & 7) << 4;
            char* rowp = lds_x + r * 128;
            *reinterpret_cast<uint4*>(rowp + ((xq * 32) ^ sw))      = pa;
            *reinterpret_cast<uint4*>(rowp + ((xq * 32 + 16) ^ sw)) = pb;
        }

        sbp += w0.x*b0.x + w0.y*b0.y + w0.z*b0.z + w0.w*b0.w
             + w1.x*b1.x + w1.y*b1.y + w1.z*b1.z + w1.w*b1.w
             + w2.x*b2.x + w2.y*b2.y + w2.z*b2.z + w2.w*b2.w
             + w3.x*b3.x + w3.y*b3.y + w3.z*b3.z + w3.w*b3.w;
        {
            char* rowp = lds_w + jrow * 128;
            uint4 pa = {pk2(w0.x, w0.y), pk2(w0.z, w0.w), pk2(w1.x, w1.y), pk2(w1.z, w1.w)};
            uint4 pb = {pk2(w2.x, w2.y), pk2(w2.z, w2.w), pk2(w3.x, w3.y), pk2(w3.z, w3.w)};
            *reinterpret_cast<uint4*>(rowp + ((jq * 32) ^ sww))      = pa;
            *reinterpret_cast<uint4*>(rowp + ((jq * 32 + 16) ^ sww)) = pb;
        }

        __syncthreads();

        #pragma unroll
        for (int ks = 0; ks < 2; ++ks) {
            bf16x8 af[4];
            bf16x8 bfr[4];
            #pragma unroll
            for (int m = 0; m < 4; ++m) {
                const int row = wv * 64 + m * 16 + l15;
                af[m] = *reinterpret_cast<const bf16x8*>(
                    lds_x + row * 128 + ((ks * 64 + lhi * 16) ^ swr));
            }
            #pragma unroll
            for (int n = 0; n < 4; ++n) {
                const int row = n * 16 + l15;
                bfr[n] = *reinterpret_cast<const bf16x8*>(
                    lds_w + row * 128 + ((ks * 64 + lhi * 16) ^ swr));
            }
            #pragma unroll
            for (int m = 0; m < 4; ++m)
                #pragma unroll
                for (int n = 0; n < 4; ++n)
                    acc[m][n] = __builtin_amdgcn_mfma_f32_16x16x32_bf16(
                        af[m], bfr[n], acc[m][n], 0, 0, 0);
        }

        __syncthreads();
    }

    sbp += __shfl_xor(sbp, 1);
    sbp += __shfl_xor(sbp, 2);
    if (jq == 0) sb_lds[jrow] = sbp;
    __syncthreads();

    float sb[4];
    #pragma unroll
    for (int n = 0; n < 4; ++n) sb[n] = sb_lds[n * 16 + l15];

    #pragma unroll
    for (int m = 0; m < 4; ++m) {
        #pragma unroll
        for (int rg = 0; rg < 4; ++rg) {
            float p = 0.f;
            #pragma unroll
            for (int n = 0; n < 4; ++n) {
                const float d = acc[m][n][rg] - sb[n];
                p += d * d;
            }
            #pragma unroll
            for (int s = 1; s < 16; s <<= 1)
                p += __shfl_xor(p, s);
            if (l15 == 0) {
                const int b = wv * 64 + m * 16 + lhi * 4 + rg;
                out[(size_t)b * CDIM + c0] = p;
            }
        }
    }
}

extern "C" void kernel_launch(void* const* d_in, const int* in_sizes, int n_in,
                              void* d_out, int out_size, void* d_ws, size_t ws_size,
                              hipStream_t stream) {
    const float* x    = (const float*)d_in[0];
    const float* w    = (const float*)d_in[1];
    const float* bias = (const float*)d_in[2];
    float* out = (float*)d_out;

    if (ws_size >= (size_t)(BDIM * NDIM * 2)) {   // 256 KB bf16 x tile images
        hipLaunchKernelGGL(Mahalanobis_xconv_kernel, dim3(64), dim3(256), 0, stream,
                           x, (uint4*)d_ws);
        hipLaunchKernelGGL(Mahalanobis_72834055405642_kernel, dim3(CDIM / 2), dim3(256),
                           0, stream, (const char*)d_ws, w, bias, out);
    } else {
        hipLaunchKernelGGL(Mahalanobis_fallback_kernel, dim3(CDIM), dim3(256),
                           0, stream, x, w, bias, out);
    }
}